// Round 14
// baseline (37.912 us; speedup 1.0000x reference)
//
#include <hip/hip_runtime.h>

// Fused: out[b, c*9+d] = sum_hw fcn[b,c,hw] * kern[c*9+d, hw], row-L2-normalized.
// B=4096, C=128, D=9, HW=64, all fp32. One kernel; fcn read once; out written once.
//
// vs R11 (31.6us, 78% of BW floor), three changes:
//  1. RB=8 rows/block via 512 thr (64 groups x 8 lanes), NCH=2, grid 512:
//     still 16 waves/CU (2 blk/CU x 8 waves) but kern L2 traffic HALVES
//     (512 x 288KB = 147MB) and all 8 lanes own a row (no idle keep-lanes).
//  2. Non-temporal fcn loads + out stores (stream-once data): keeps the
//     4MB/XCD L2 for kern, which the fcn stream otherwise thrashes.
//  3. LDS tile row stride 289 float4 (=1156 floats, %32=4): scalar keep-writes
//     land on banks 4l+9c+d -> no systematic conflict (1152 would be 8-way).
// __launch_bounds__(512,2) = 128-VGPR cap (toolchain decode: cap ~= 256/N;
// N>=3 is the 64-cap spill trap of R5/R8/R10). Natural ~105 VGPR fits.
// reduce8 = 3 DPP adds (quad_perm xor1/xor2 + row_half_mirror), zero DS ops.
// Spill tripwire: WRITE_SIZE must stay ~18.5 MB.

using vf4 = __attribute__((ext_vector_type(4))) float;

constexpr int B_TOT = 4096;
constexpr int C_CH  = 128;
constexpr int D_EMB = 9;
constexpr int THREADS = 512;
constexpr int GPB = 64;   // concurrent channels (groups) per block
constexpr int NCH = 2;    // channel iterations per group
constexpr int RB  = 8;    // rows per block (= lanes per group)
constexpr int ROW4 = C_CH * D_EMB / 4;   // 288 float4 per output row
constexpr int RSTR4 = ROW4 + 1;          // 289: padded LDS row stride (float4)

__device__ __forceinline__ float reduce8_hw(float p) {
    // sum over the 8-lane group, VALU-only DPP (R7-proven)
    p += __int_as_float(__builtin_amdgcn_mov_dpp(__float_as_int(p), 0xB1,  0xf, 0xf, true)); // xor1
    p += __int_as_float(__builtin_amdgcn_mov_dpp(__float_as_int(p), 0x4E,  0xf, 0xf, true)); // xor2
    p += __int_as_float(__builtin_amdgcn_mov_dpp(__float_as_int(p), 0x141, 0xf, 0xf, true)); // xor4 (row_half_mirror)
    return p;
}

__global__ __launch_bounds__(THREADS, 2)
void esenc_fused(const float* __restrict__ fcn,
                 const float* __restrict__ kern,
                 float* __restrict__ out) {
    __shared__ __align__(16) float tile[RB * RSTR4 * 4];   // 36,992 B
    __shared__ float red[8 * RB];                           // 8 waves x 8 rows
    __shared__ float invn[RB];

    const int tid = threadIdx.x;
    const int l   = tid & 7;        // hw-slice lane = owned row id
    const int g   = tid >> 3;       // group 0..63
    const int w   = tid >> 6;       // wave 0..7
    const unsigned b0 = blockIdx.x * RB;

    const vf4* kern4 = (const vf4*)kern;
    const vf4* f4    = (const vf4*)fcn;

    float s = 0.0f;                 // row-l sumsq partial over this thread's channels

#pragma unroll
    for (int ch = 0; ch < NCH; ++ch) {
        const unsigned c = (unsigned)(ch * GPB + g);

        // fcn rows resident: 8 rows x 2 float4, non-temporal (stream-once)
        vf4 f0[RB], f1[RB];
#pragma unroll
        for (int r = 0; r < RB; ++r) {
            const unsigned fb = ((b0 + (unsigned)r) * C_CH + c) * 16u;
            f0[r] = __builtin_nontemporal_load(f4 + fb + l);
            f1[r] = __builtin_nontemporal_load(f4 + fb + 8u + l);
        }

        float keep[D_EMB];          // every lane keeps row l
#pragma unroll
        for (int d = 0; d < D_EMB; ++d) {
            const unsigned kb = (c * D_EMB + (unsigned)d) * 16u;
            const vf4 k0 = kern4[kb + l];     // cached (L2-hot) kern reads
            const vf4 k1 = kern4[kb + 8u + l];
#pragma unroll
            for (int r = 0; r < RB; ++r) {
                float t;
                t = f0[r].x * k0.x;
                t = fmaf(f0[r].y, k0.y, t);
                t = fmaf(f0[r].z, k0.z, t);
                t = fmaf(f0[r].w, k0.w, t);
                t = fmaf(f1[r].x, k1.x, t);
                t = fmaf(f1[r].y, k1.y, t);
                t = fmaf(f1[r].z, k1.z, t);
                t = fmaf(f1[r].w, k1.w, t);
                t = reduce8_hw(t);
                if (l == r) keep[d] = t;
            }
        }

        // stream raw results to LDS (all 8 lanes, row l), accumulate sumsq
#pragma unroll
        for (int d = 0; d < D_EMB; ++d) {
            tile[l * (RSTR4 * 4) + (int)c * D_EMB + d] = keep[d];
            s = fmaf(keep[d], keep[d], s);
        }
    }

    // row sumsq: reduce over the wave's 8 groups (l preserved by xor 8/16/32)
    s += __shfl_xor(s, 8,  64);
    s += __shfl_xor(s, 16, 64);
    s += __shfl_xor(s, 32, 64);
    if ((tid & 63) < RB) red[w * RB + l] = s;
    __syncthreads();
    if (tid < RB) {
        float t = 0.0f;
#pragma unroll
        for (int j = 0; j < 8; ++j) t += red[j * RB + tid];
        invn[tid] = 1.0f / sqrtf(t + 1e-10f);
    }
    __syncthreads();

    // coalesced non-temporal store: 8 contiguous rows = 2304 float4
    const vf4* t4 = (const vf4*)tile;
    vf4* o4 = (vf4*)out;
#pragma unroll
    for (int j = 0; j < (RB * ROW4 + THREADS - 1) / THREADS; ++j) {
        const int i = tid + j * THREADS;
        if (i < RB * ROW4) {
            const int row = i / ROW4;
            const int off = i - row * ROW4;
            const float inv = invn[row];
            vf4 v = t4[row * RSTR4 + off];
            v.x *= inv; v.y *= inv; v.z *= inv; v.w *= inv;
            __builtin_nontemporal_store(v, o4 + (size_t)(b0 + row) * ROW4 + off);
        }
    }
}

extern "C" void kernel_launch(void* const* d_in, const int* in_sizes, int n_in,
                              void* d_out, int out_size, void* d_ws, size_t ws_size,
                              hipStream_t stream) {
    const float* fcn  = (const float*)d_in[0];   // [4096,128,8,8] f32
    const float* kern = (const float*)d_in[1];   // [1,1152,8,8]  f32
    float* out = (float*)d_out;                  // [4096,1152]   f32

    dim3 grid(B_TOT / RB), block(THREADS);       // 512 blocks x 512 thr
    hipLaunchKernelGGL(esenc_fused, grid, block, 0, stream, fcn, kern, out);
}

// Round 15
// 31.490 us; speedup vs baseline: 1.2039x; 1.2039x over previous
//
#include <hip/hip_runtime.h>

// Fused: out[b, c*9+d] = sum_hw fcn[b,c,hw] * kern[c*9+d, hw], row-L2-normalized.
// B=4096, C=128, D=9, HW=64, all fp32. One kernel; fcn read once; out written once.
//
// R11 verbatim — measured best (31.6us = 78% of the 24.5us BW floor).
// Ledger of tested-and-rejected variants:
//   R12 RB=2 (32-wave push): 36.2us — kern L2 traffic doubles, occupancy step
//        function (m69) means VGPR 65..128 all give 16 waves/CU anyway.
//   R13 +explicit prefetch: 32.0us — neutral; 16 waves/CU already hides it.
//   R14 RB=8 + nontemporal: 37.9us — NT raises load latency (no pollution win
//        for read-once data); f0/f1[8]=64 resident VGPR chokes the 128 cap.
// Design:
//  - block = 4 rows x 128 channels, 256 thr = 32 groups x 8 lanes, NCH=4
//  - grid = 1024 = 4 blocks/CU x 4 waves = 16 waves/CU (VGPR 65..128 band)
//  - fcn rows resident (8 float4/ch-iter, read ONCE), kern transient per-d
//  - __launch_bounds__(256,2): cap 128 (toolchain decode: cap ~= 256/N;
//    N>=4 = 64-reg cap = spill trap, R5/R8/R10)
//  - keep[] zero-init; lanes l<4 own rows; out staged via LDS, coalesced f4
//  - reduce8 = 3 DPP adds (quad_perm xor1/xor2 + row_half_mirror), zero DS ops

constexpr int B_TOT = 4096;
constexpr int C_CH  = 128;
constexpr int D_EMB = 9;
constexpr int THREADS = 256;
constexpr int GPB = 32;   // concurrent channels (groups) per block
constexpr int NCH = 4;    // channel iterations per group
constexpr int RB  = 4;    // rows per block
constexpr int ROWF = C_CH * D_EMB;   // 1152 floats per output row

__device__ __forceinline__ float reduce8_hw(float p) {
    // sum over the 8-lane group, VALU-only DPP (R7-proven)
    p += __int_as_float(__builtin_amdgcn_mov_dpp(__float_as_int(p), 0xB1,  0xf, 0xf, true)); // xor1
    p += __int_as_float(__builtin_amdgcn_mov_dpp(__float_as_int(p), 0x4E,  0xf, 0xf, true)); // xor2
    p += __int_as_float(__builtin_amdgcn_mov_dpp(__float_as_int(p), 0x141, 0xf, 0xf, true)); // xor4 (row_half_mirror)
    return p;
}

__global__ __launch_bounds__(THREADS, 2)
void esenc_fused(const float* __restrict__ fcn,
                 const float* __restrict__ kern,
                 float* __restrict__ out) {
    __shared__ __align__(16) float tile[RB * ROWF];   // 18432 B
    __shared__ float red[4 * RB];                      // 4 waves x 4 rows
    __shared__ float invn[RB];

    const int tid = threadIdx.x;
    const int l   = tid & 7;        // hw-slice lane; rows 0..3 kept by lanes 0..3
    const int g   = tid >> 3;       // group 0..31
    const int w   = tid >> 6;       // wave 0..3
    const unsigned b0 = blockIdx.x * RB;

    const float4* kern4 = (const float4*)kern;
    const float4* f4    = (const float4*)fcn;

    float keep[NCH][D_EMB] = {};    // lanes 4..7 stay zero (shfl contributions valid)

#pragma unroll
    for (int ch = 0; ch < NCH; ++ch) {
        const unsigned c = (unsigned)(ch * GPB + g);

        // fcn rows resident: 4 rows x 2 float4 (read once, 32 VGPR)
        float4 f0[RB], f1[RB];
#pragma unroll
        for (int r = 0; r < RB; ++r) {
            const unsigned fb = ((b0 + (unsigned)r) * C_CH + c) * 16u;
            f0[r] = f4[fb + l];
            f1[r] = f4[fb + 8u + l];
        }

#pragma unroll
        for (int d = 0; d < D_EMB; ++d) {
            const unsigned kb = (c * D_EMB + (unsigned)d) * 16u;
            const float4 k0 = kern4[kb + l];     // transient: 8 VGPR
            const float4 k1 = kern4[kb + 8u + l];
#pragma unroll
            for (int r = 0; r < RB; ++r) {
                float t;
                t = f0[r].x * k0.x;
                t = fmaf(f0[r].y, k0.y, t);
                t = fmaf(f0[r].z, k0.z, t);
                t = fmaf(f0[r].w, k0.w, t);
                t = fmaf(f1[r].x, k1.x, t);
                t = fmaf(f1[r].y, k1.y, t);
                t = fmaf(f1[r].z, k1.z, t);
                t = fmaf(f1[r].w, k1.w, t);
                t = reduce8_hw(t);
                if (l == r) keep[ch][d] = t;
            }
        }
    }

    // row sumsq: lanes l<4 hold row l's 4-channel partial; others contribute 0
    float s = 0.0f;
#pragma unroll
    for (int ch = 0; ch < NCH; ++ch)
#pragma unroll
        for (int d = 0; d < D_EMB; ++d)
            s = fmaf(keep[ch][d], keep[ch][d], s);

    s += __shfl_xor(s, 8,  64);   // reduce over the wave's 8 groups
    s += __shfl_xor(s, 16, 64);
    s += __shfl_xor(s, 32, 64);
    if ((tid & 63) < RB) red[w * RB + l] = s;

    // stage raw results into LDS (lanes l<4 only)
    if (l < RB) {
#pragma unroll
        for (int ch = 0; ch < NCH; ++ch) {
            const int c = ch * GPB + g;
#pragma unroll
            for (int d = 0; d < D_EMB; ++d)
                tile[l * ROWF + c * D_EMB + d] = keep[ch][d];
        }
    }
    __syncthreads();
    if (tid < RB)
        invn[tid] = 1.0f / sqrtf(red[tid] + red[RB + tid] + red[2 * RB + tid]
                                 + red[3 * RB + tid] + 1e-10f);
    __syncthreads();

    // coalesced store: 4 contiguous rows = 1152 float4
    const float4* t4 = (const float4*)tile;
    float4* o4 = (float4*)(out + (size_t)b0 * ROWF);
#pragma unroll
    for (int j = 0; j < (RB * ROWF / 4) / THREADS + 1; ++j) {
        const int i = tid + j * THREADS;
        if (i < RB * ROWF / 4) {
            const float inv = invn[i / (ROWF / 4)];
            float4 v = t4[i];
            v.x *= inv; v.y *= inv; v.z *= inv; v.w *= inv;
            o4[i] = v;
        }
    }
}

extern "C" void kernel_launch(void* const* d_in, const int* in_sizes, int n_in,
                              void* d_out, int out_size, void* d_ws, size_t ws_size,
                              hipStream_t stream) {
    const float* fcn  = (const float*)d_in[0];   // [4096,128,8,8] f32
    const float* kern = (const float*)d_in[1];   // [1,1152,8,8]  f32
    float* out = (float*)d_out;                  // [4096,1152]   f32

    dim3 grid(B_TOT / RB), block(THREADS);       // 1024 blocks
    hipLaunchKernelGGL(esenc_fused, grid, block, 0, stream, fcn, kern, out);
}